// Round 4
// baseline (119.855 us; speedup 1.0000x reference)
//
#include <hip/hip_runtime.h>
#include <math.h>

// Problem constants (from reference setup_inputs)
#define NQ 2048
#define NB 8192
#define DIM 32

#define LOG2E 1.44269504088896340736f

typedef _Float16 half8 __attribute__((ext_vector_type(8)));
typedef float    f32x4 __attribute__((ext_vector_type(4)));

// ---------------- workspace layout (bytes) ----------------
#define WS_ACC 0            // 2*NQ f32   (16384 B)
#define WS_Q2  16384        // NQ   f32   (8192 B)
#define WS_B2  24576        // NB   f32   (32768 B)
#define WS_XQH 57344        // NQ*DIM f16 (131072 B)
#define WS_XBH 188416       // NB*DIM f16 (524288 B)

// Convert x*w to f16 and compute row norms FROM THE ROUNDED VALUES, so the
// MFMA-computed d2 = ||Aq - Ab||^2 has no representation-mismatch cancellation.
// Also zeroes the atomic accumulators (ws is poisoned 0xAA by the harness).
__global__ __launch_bounds__(256) void relnw_pre(
    const float* __restrict__ xq, const float* __restrict__ xb,
    const float* __restrict__ w,
    _Float16* __restrict__ XQh, _Float16* __restrict__ XBh,
    float* __restrict__ q2, float* __restrict__ b2,
    float* __restrict__ acc)
{
    int i = blockIdx.x * 256 + threadIdx.x;
    if (i < 2 * NQ) acc[i] = 0.f;            // replaces separate memset launch
    const float* src; _Float16* dst; float* s2;
    if (i < NQ)            { src = xq + (size_t)i * DIM;  dst = XQh + (size_t)i * DIM;  s2 = q2 + i; }
    else if (i < NQ + NB)  { int j = i - NQ;
                             src = xb + (size_t)j * DIM;  dst = XBh + (size_t)j * DIM;  s2 = b2 + j; }
    else return;
    float s = 0.f;
#pragma unroll
    for (int d = 0; d < DIM; ++d) {
        float t = src[d] * w[d];       // w uniform -> s_load
        _Float16 h = (_Float16)t;
        float th = (float)h;
        s = fmaf(th, th, s);
        dst[d] = h;
    }
    *s2 = s;
}

// Main kernel: grid (16, 64), 256 threads (4 waves), 1024 blocks (4/CU).
// Wave task: TWO 16-query tiles (32 queries, blockIdx.y) x 128-bg chunk
// (chunk = blockIdx.x*4 + wave), processed as 8 MFMA tiles of 16 bgs.
// Each bfrag/yb/b2 load now serves 32 queries (2 MFMAs), and each iteration
// issues 8 independent r loads -> better MLP for latency hiding.
// C/D layout (16x16x32_f16): col = lane&15 (bg), row = (lane>>4)*4+reg (query).
#define BT_PER_WAVE 8
#define BG_PER_WAVE (BT_PER_WAVE * 16)   // 128
#define QT 2                              // q-tiles per wave

__global__ __launch_bounds__(256) void relnw_main(
    const _Float16* __restrict__ XQh,  // (NQ, DIM)
    const _Float16* __restrict__ XBh,  // (NB, DIM)
    const float* __restrict__ q2,      // (NQ,)
    const float* __restrict__ b2,      // (NB,)
    const float* __restrict__ yb,      // (NB,)
    const float* __restrict__ r,       // (NQ, NB)
    const float* __restrict__ sigma,   // (1,)
    const float* __restrict__ rscale,  // (1,)
    float* __restrict__ acc)           // [0:NQ]=sum_k, [NQ:2NQ]=sum_k*y
{
    const int tid  = threadIdx.x;
    const int lane = tid & 63;
    const int wid  = tid >> 6;
    const int m    = lane & 15;   // A row (query) / B col (bg) / C col (bg)
    const int quad = lane >> 4;   // 0..3

    const int q0     = blockIdx.y * (16 * QT);
    const int bstart = (blockIdx.x * 4 + wid) * BG_PER_WAVE;

    const float c1 = -LOG2E / sigma[0];   // coeff on dist (log2 space)
    const float c2 =  LOG2E * rscale[0];  // coeff on r

    // A fragments for this wave's 2 query tiles (fixed across the b-loop)
    half8 afrag[QT];
    float q2r[QT][4];
#pragma unroll
    for (int t = 0; t < QT; ++t) {
        afrag[t] = *(const half8*)(XQh + (size_t)(q0 + t * 16 + m) * DIM + quad * 8);
#pragma unroll
        for (int g = 0; g < 4; ++g) q2r[t][g] = q2[q0 + t * 16 + quad * 4 + g];
    }

    const _Float16* xbp = XBh + (size_t)(bstart + m) * DIM + quad * 8;
    const float*    rp  = r + (size_t)(q0 + quad * 4) * NB + bstart + m;

    float sk[QT][4]  = {};
    float sky[QT][4] = {};

#pragma unroll
    for (int it = 0; it < BT_PER_WAVE; ++it) {
        const int bc = bstart + it * 16 + m;            // this lane's bg col
        const half8 bfrag = *(const half8*)(xbp + (size_t)it * 16 * DIM);
        const float yv  = yb[bc];
        const float b2v = b2[bc];
        float rr[QT][4];
#pragma unroll
        for (int t = 0; t < QT; ++t)
#pragma unroll
            for (int g = 0; g < 4; ++g)
                rr[t][g] = rp[(size_t)(t * 16 + g) * NB + it * 16];

#pragma unroll
        for (int t = 0; t < QT; ++t) {
            f32x4 dot = __builtin_amdgcn_mfma_f32_16x16x32_f16(
                afrag[t], bfrag, (f32x4){0.f, 0.f, 0.f, 0.f}, 0, 0, 0);
#pragma unroll
            for (int g = 0; g < 4; ++g) {
                float d2 = fmaf(-2.f, dot[g], q2r[t][g] + b2v);
                d2 = fmaxf(d2, 0.f);
                float dist = __builtin_amdgcn_sqrtf(d2);
                float e = fmaf(dist, c1, rr[t][g] * c2); // log2-space exponent
                float k = __builtin_amdgcn_exp2f(e);
                sk[t][g] += k;
                sky[t][g] = fmaf(k, yv, sky[t][g]);
            }
        }
    }

    // Reduce across the 16 bg-columns (low 4 lane bits), once per wave.
#pragma unroll
    for (int off = 1; off <= 8; off <<= 1) {
#pragma unroll
        for (int t = 0; t < QT; ++t)
#pragma unroll
            for (int g = 0; g < 4; ++g) {
                sk[t][g]  += __shfl_xor(sk[t][g],  off, 64);
                sky[t][g] += __shfl_xor(sky[t][g], off, 64);
            }
    }
    if (m == 0) {
#pragma unroll
        for (int t = 0; t < QT; ++t)
#pragma unroll
            for (int g = 0; g < 4; ++g) {
                int q = q0 + t * 16 + quad * 4 + g;
                atomicAdd(acc + q,      sk[t][g]);
                atomicAdd(acc + NQ + q, sky[t][g]);
            }
    }
}

__global__ __launch_bounds__(256) void relnw_finalize(
    const float* __restrict__ acc, float* __restrict__ out)
{
    int q = blockIdx.x * 256 + threadIdx.x;
    if (q < NQ)
        out[q] = acc[NQ + q] / (acc[q] + 1e-8f);
}

extern "C" void kernel_launch(void* const* d_in, const int* in_sizes, int n_in,
                              void* d_out, int out_size, void* d_ws, size_t ws_size,
                              hipStream_t stream) {
    const float* xb     = (const float*)d_in[0]; // (8192,32)
    const float* yb     = (const float*)d_in[1]; // (8192,)
    const float* xq     = (const float*)d_in[2]; // (2048,32)
    const float* r      = (const float*)d_in[3]; // (2048,8192)
    const float* sigma  = (const float*)d_in[4]; // (1,)
    const float* rscale = (const float*)d_in[5]; // (1,)
    const float* w      = (const float*)d_in[6]; // (32,)
    float* out = (float*)d_out;

    char* ws = (char*)d_ws;
    float*    acc = (float*)(ws + WS_ACC);
    float*    q2  = (float*)(ws + WS_Q2);
    float*    b2  = (float*)(ws + WS_B2);
    _Float16* XQh = (_Float16*)(ws + WS_XQH);
    _Float16* XBh = (_Float16*)(ws + WS_XBH);

    relnw_pre<<<(NQ + NB + 255) / 256, 256, 0, stream>>>(xq, xb, w, XQh, XBh, q2, b2, acc);

    dim3 grid(NB / (4 * BG_PER_WAVE), NQ / (16 * QT));  // (16, 64) = 1024 blocks
    relnw_main<<<grid, 256, 0, stream>>>(XQh, XBh, q2, b2, yb, r, sigma, rscale, acc);

    relnw_finalize<<<(NQ + 255) / 256, 256, 0, stream>>>(acc, out);
}